// Round 1
// baseline (1536.224 us; speedup 1.0000x reference)
//
#include <hip/hip_runtime.h>
#include <cmath>

#define HH 80
#define WW 80
#define HWSZ 6400   // 80*80

// ---------------------------------------------------------------------------
// activations: 0=none 1=relu 2=tanh 3=sigmoid 4=softplus
__device__ __forceinline__ float apply_act(float x, int act) {
    switch (act) {
        case 1: return fmaxf(x, 0.f);
        case 2: return tanhf(x);
        case 3: return 1.f / (1.f + expf(-x));
        case 4: return x > 0.f ? x + log1pf(expf(-x)) : log1pf(expf(x));
        default: return x;
    }
}

// ---------------------------------------------------------------------------
// Generic 3x3 pad-1 conv tile: 16x16 spatial tile, NOUT out-channels per block,
// 4 input channels staged in LDS per barrier pair.
// inA/inB: channel-split input (channel c < CA from inA else inB), already
// offset to batch b. w: [Cout][Cin][9]. out: already offset to batch b,
// layout [Cout][HW].
template<int NOUT>
__device__ __forceinline__ void conv3x3_tile(
    const float* __restrict__ inA, const float* __restrict__ inB,
    int CA, int CB,
    const float* __restrict__ w, const float* __restrict__ bias,
    float* __restrict__ out, int Cout, int coBase, int act, int tileIdx)
{
    const int tid = threadIdx.x;
    const int ty0 = (tileIdx / 5) * 16;
    const int tx0 = (tileIdx % 5) * 16;
    const int py = tid >> 4, px = tid & 15;
    const int oy = ty0 + py, ox = tx0 + px;
    const int Cin = CA + CB;
    const int Cin9 = Cin * 9;

    __shared__ float patch[4][18 * 18];

    float acc[NOUT];
#pragma unroll
    for (int j = 0; j < NOUT; ++j) acc[j] = 0.f;

    for (int ci = 0; ci < Cin; ci += 4) {
        // stage 4 input-channel patches (18x18 with zero pad)
        for (int i = tid; i < 4 * 324; i += 256) {
            int q = i / 324;
            int r = i - q * 324;
            int gy = ty0 - 1 + r / 18;
            int gx = tx0 - 1 + (r % 18);
            int cc = ci + q;
            const float* src = (cc < CA) ? (inA + cc * HWSZ)
                                         : (inB + (cc - CA) * HWSZ);
            float v = 0.f;
            if (gy >= 0 && gy < HH && gx >= 0 && gx < WW) v = src[gy * WW + gx];
            patch[q][r] = v;
        }
        __syncthreads();

#pragma unroll
        for (int q = 0; q < 4; ++q) {
            const float t0 = patch[q][(py + 0) * 18 + px + 0];
            const float t1 = patch[q][(py + 0) * 18 + px + 1];
            const float t2 = patch[q][(py + 0) * 18 + px + 2];
            const float t3 = patch[q][(py + 1) * 18 + px + 0];
            const float t4 = patch[q][(py + 1) * 18 + px + 1];
            const float t5 = patch[q][(py + 1) * 18 + px + 2];
            const float t6 = patch[q][(py + 2) * 18 + px + 0];
            const float t7 = patch[q][(py + 2) * 18 + px + 1];
            const float t8 = patch[q][(py + 2) * 18 + px + 2];
#pragma unroll
            for (int j = 0; j < NOUT; ++j) {
                // clamp so OOB weight reads never happen when Cout % NOUT != 0
                int co = min(coBase + j, Cout - 1);
                const float* wj = w + co * Cin9 + (ci + q) * 9;
                float s = acc[j];
                s = fmaf(wj[0], t0, s);
                s = fmaf(wj[1], t1, s);
                s = fmaf(wj[2], t2, s);
                s = fmaf(wj[3], t3, s);
                s = fmaf(wj[4], t4, s);
                s = fmaf(wj[5], t5, s);
                s = fmaf(wj[6], t6, s);
                s = fmaf(wj[7], t7, s);
                s = fmaf(wj[8], t8, s);
                acc[j] = s;
            }
        }
        __syncthreads();
    }

#pragma unroll
    for (int j = 0; j < NOUT; ++j) {
        int co = coBase + j;
        if (co < Cout) {
            float v = apply_act(acc[j] + bias[co], act);
            out[co * HWSZ + oy * WW + ox] = v;
        }
    }
}

// ---------------------------------------------------------------------------
// Fused first-layer convs: ow1 / sw1 / mw1, all 512->64, all ReLU, same input.
// grid: (25 tiles, 24 = 3 branches * 8 co-tiles, B)
__global__ __launch_bounds__(256) void bigconv_kernel(
    const float* __restrict__ rgb, const float* __restrict__ th,
    const float* __restrict__ ow1, const float* __restrict__ ob1,
    const float* __restrict__ sw1, const float* __restrict__ sb1,
    const float* __restrict__ mw1, const float* __restrict__ mb1,
    float* __restrict__ h1all)
{
    const int b = blockIdx.z;
    const int branch = blockIdx.y >> 3;
    const int coB = (blockIdx.y & 7) * 8;
    const float* w = (branch == 0) ? ow1 : (branch == 1) ? sw1 : mw1;
    const float* bi = (branch == 0) ? ob1 : (branch == 1) ? sb1 : mb1;
    conv3x3_tile<8>(rgb + b * 256 * HWSZ, th + b * 256 * HWSZ, 256, 256,
                    w, bi, h1all + (b * 192 + branch * 64) * HWSZ,
                    64, coB, /*relu*/ 1, blockIdx.x);
}

// Fused second-layer convs: conv2 (64->64 relu), sw2 (64->1 softplus),
// mw2 (64->72 sigmoid). grid: (25, 18 = 8 + 1 + 9, B)
__global__ __launch_bounds__(256) void midconv_kernel(
    const float* __restrict__ h1all,
    const float* __restrict__ ow2, const float* __restrict__ ob2,
    const float* __restrict__ sw2, const float* __restrict__ sb2,
    const float* __restrict__ mw2, const float* __restrict__ mb2,
    float* __restrict__ h2, float* __restrict__ sbuf, float* __restrict__ modb)
{
    const int b = blockIdx.z;
    const int y = blockIdx.y;
    const float* in;
    const float* w;
    const float* bi;
    float* outp;
    int Cout, coB, act;
    if (y < 8) {
        in = h1all + (b * 192 + 0) * HWSZ; w = ow2; bi = ob2;
        outp = h2 + b * 64 * HWSZ; Cout = 64; coB = y * 8; act = 1;
    } else if (y == 8) {
        in = h1all + (b * 192 + 64) * HWSZ; w = sw2; bi = sb2;
        outp = sbuf + b * 1 * HWSZ; Cout = 1; coB = 0; act = 4;
    } else {
        in = h1all + (b * 192 + 128) * HWSZ; w = mw2; bi = mb2;
        outp = modb + b * 72 * HWSZ; Cout = 72; coB = (y - 9) * 8; act = 3;
    }
    conv3x3_tile<8>(in, in, 64, 0, w, bi, outp, Cout, coB, act, blockIdx.x);
}

// conv3: 64 -> 144, tanh. grid: (25, 18, B)
__global__ __launch_bounds__(256) void conv3_kernel(
    const float* __restrict__ h2,
    const float* __restrict__ ow3, const float* __restrict__ ob3,
    float* __restrict__ baseoff)
{
    const int b = blockIdx.z;
    conv3x3_tile<8>(h2 + b * 64 * HWSZ, h2 + b * 64 * HWSZ, 64, 0,
                    ow3, ob3, baseoff + b * 144 * HWSZ,
                    144, blockIdx.y * 8, /*tanh*/ 2, blockIdx.x);
}

// ---------------------------------------------------------------------------
// Global average pool: one block per (channel, b). grid (512, B)
__global__ __launch_bounds__(256) void pool_kernel(
    const float* __restrict__ rgb, const float* __restrict__ th,
    float* __restrict__ xp)
{
    const int c = blockIdx.x, b = blockIdx.y, tid = threadIdx.x;
    const float* src = (c < 256) ? rgb + (b * 256 + c) * HWSZ
                                 : th + (b * 256 + (c - 256)) * HWSZ;
    float s = 0.f;
    for (int i = tid; i < HWSZ; i += 256) s += src[i];
#pragma unroll
    for (int off = 32; off; off >>= 1) s += __shfl_down(s, off, 64);
    __shared__ float red[4];
    if ((tid & 63) == 0) red[tid >> 6] = s;
    __syncthreads();
    if (tid == 0) xp[b * 512 + c] = (red[0] + red[1] + red[2] + red[3]) * (1.f / HWSZ);
}

// Tiny MLPs for g (512->32->1) and c (512->256->8), plus softmax of 3 scalars.
// scal layout: [0..2]=wts, [3..4]=g per b, [5..20]=c per (b, group)
__global__ __launch_bounds__(256) void gc_kernel(
    const float* __restrict__ xp,
    const float* __restrict__ gw1, const float* __restrict__ gb1,
    const float* __restrict__ gw2, const float* __restrict__ gb2,
    const float* __restrict__ cw1, const float* __restrict__ cb1,
    const float* __restrict__ cw2, const float* __restrict__ cb2,
    const float* __restrict__ wglob, const float* __restrict__ wchan,
    const float* __restrict__ wspat,
    float* __restrict__ scal)
{
    const int tid = threadIdx.x;
    const int lane = tid & 63;
    const int wv = tid >> 6;
    __shared__ float xs[512];
    __shared__ float hg[32];
    __shared__ float hc[256];

    if (tid == 0) {
        float a = wglob[0], bb = wchan[0], cc = wspat[0];
        float mx = fmaxf(a, fmaxf(bb, cc));
        float ea = expf(a - mx), eb = expf(bb - mx), ec = expf(cc - mx);
        float s = ea + eb + ec;
        scal[0] = ea / s; scal[1] = eb / s; scal[2] = ec / s;
    }

    for (int b = 0; b < 2; ++b) {
        xs[tid] = xp[b * 512 + tid];
        xs[tid + 256] = xp[b * 512 + 256 + tid];
        __syncthreads();
        // hc rows (256 x dot-512), one wave per row
        for (int j = wv; j < 256; j += 4) {
            float s = 0.f;
            for (int i = lane; i < 512; i += 64) s = fmaf(cw1[j * 512 + i], xs[i], s);
#pragma unroll
            for (int o = 32; o; o >>= 1) s += __shfl_down(s, o, 64);
            if (lane == 0) hc[j] = fmaxf(s + cb1[j], 0.f);
        }
        // hg rows (32 x dot-512)
        for (int j = wv; j < 32; j += 4) {
            float s = 0.f;
            for (int i = lane; i < 512; i += 64) s = fmaf(gw1[j * 512 + i], xs[i], s);
#pragma unroll
            for (int o = 32; o; o >>= 1) s += __shfl_down(s, o, 64);
            if (lane == 0) hg[j] = fmaxf(s + gb1[j], 0.f);
        }
        __syncthreads();
        // c: 8 rows x dot-256
        for (int j = wv; j < 8; j += 4) {
            float s = 0.f;
            for (int i = lane; i < 256; i += 64) s = fmaf(cw2[j * 256 + i], hc[i], s);
#pragma unroll
            for (int o = 32; o; o >>= 1) s += __shfl_down(s, o, 64);
            if (lane == 0) scal[5 + b * 8 + j] = apply_act(s + cb2[j], 4);
        }
        // g: dot-32
        if (wv == 1) {
            float s = (lane < 32) ? gw2[lane] * hg[lane] : 0.f;
#pragma unroll
            for (int o = 32; o; o >>= 1) s += __shfl_down(s, o, 64);
            if (lane == 0) scal[3 + b] = apply_act(s + gb2[0], 4);
        }
        __syncthreads();
    }
}

// ---------------------------------------------------------------------------
// Modulated deformable conv. One thread = one pixel of one group; 32 output
// channel accumulators. Offsets scaled in-kernel by combined attention.
// grid: (25, G=8, B)
__global__ __launch_bounds__(256) void dcn_kernel(
    const float* __restrict__ rgb, const float* __restrict__ baseoff,
    const float* __restrict__ modb, const float* __restrict__ sbuf,
    const float* __restrict__ scal,
    const float* __restrict__ dw, const float* __restrict__ db,
    float* __restrict__ out)
{
    const int tid = threadIdx.x;
    const int p = blockIdx.x * 256 + tid;
    const int g = blockIdx.y, b = blockIdx.z;
    const int h = p / 80, wp = p - h * 80;

    const float w0 = scal[0], w1 = scal[1], w2 = scal[2];
    const float gv = scal[3 + b];
    const float sv = sbuf[b * HWSZ + p];
    const float basegs = w0 * gv + w2 * sv;

    const float* xg = rgb + (b * 256 + g * 32) * HWSZ;
    const float* wt = dw + (g * 32) * 32 * 9;   // [32 o][32 c][9 k]

    float acc[32];
#pragma unroll
    for (int o = 0; o < 32; ++o) acc[o] = 0.f;

    for (int k = 0; k < 9; ++k) {
        const int chy = g * 18 + k * 2;
        const int chx = chy + 1;
        const int jy = (chy % 72) / 9;
        const int jx = (chx % 72) / 9;
        const float cmy = basegs + w1 * scal[5 + b * 8 + jy];
        const float cmx = basegs + w1 * scal[5 + b * 8 + jx];
        const float offy = baseoff[(b * 144 + chy) * HWSZ + p] * cmy;
        const float offx = baseoff[(b * 144 + chx) * HWSZ + p] * cmx;

        const float py = (float)(h + (k / 3) - 1) + offy;
        const float px = (float)(wp + (k % 3) - 1) + offx;
        const float y0f = floorf(py), x0f = floorf(px);
        const float ly = py - y0f, lx = px - x0f;
        const int iy0 = (int)y0f, ix0 = (int)x0f;
        const int iy1 = iy0 + 1, ix1 = ix0 + 1;

        const float m = modb[(b * 72 + g * 9 + k) * HWSZ + p];

        const float vy0 = (iy0 >= 0 && iy0 < HH) ? 1.f : 0.f;
        const float vy1 = (iy1 >= 0 && iy1 < HH) ? 1.f : 0.f;
        const float vx0 = (ix0 >= 0 && ix0 < WW) ? 1.f : 0.f;
        const float vx1 = (ix1 >= 0 && ix1 < WW) ? 1.f : 0.f;
        const int cy0 = min(max(iy0, 0), HH - 1), cy1 = min(max(iy1, 0), HH - 1);
        const int cx0 = min(max(ix0, 0), WW - 1), cx1 = min(max(ix1, 0), WW - 1);

        const float w00 = (1.f - ly) * (1.f - lx) * vy0 * vx0 * m;
        const float w01 = (1.f - ly) * lx * vy0 * vx1 * m;
        const float w10 = ly * (1.f - lx) * vy1 * vx0 * m;
        const float w11 = ly * lx * vy1 * vx1 * m;

        const int i00 = cy0 * WW + cx0, i01 = cy0 * WW + cx1;
        const int i10 = cy1 * WW + cx0, i11 = cy1 * WW + cx1;

#pragma unroll 8
        for (int c = 0; c < 32; ++c) {
            const float* xc = xg + c * HWSZ;
            float v = w00 * xc[i00] + w01 * xc[i01] + w10 * xc[i10] + w11 * xc[i11];
            const float* wck = wt + c * 9 + k;
#pragma unroll
            for (int o = 0; o < 32; ++o) acc[o] = fmaf(wck[o * 288], v, acc[o]);
        }
    }

#pragma unroll
    for (int o = 0; o < 32; ++o)
        out[(b * 256 + g * 32 + o) * HWSZ + p] = acc[o] + db[g * 32 + o];
}

// ---------------------------------------------------------------------------
extern "C" void kernel_launch(void* const* d_in, const int* in_sizes, int n_in,
                              void* d_out, int out_size, void* d_ws, size_t ws_size,
                              hipStream_t stream) {
    const float* rgb  = (const float*)d_in[0];
    const float* th   = (const float*)d_in[1];
    const float* ow1  = (const float*)d_in[2];
    const float* ob1  = (const float*)d_in[3];
    const float* ow2  = (const float*)d_in[4];
    const float* ob2  = (const float*)d_in[5];
    const float* ow3  = (const float*)d_in[6];
    const float* ob3  = (const float*)d_in[7];
    const float* gw1  = (const float*)d_in[8];
    const float* gb1  = (const float*)d_in[9];
    const float* gw2  = (const float*)d_in[10];
    const float* gb2  = (const float*)d_in[11];
    const float* cw1  = (const float*)d_in[12];
    const float* cb1  = (const float*)d_in[13];
    const float* cw2  = (const float*)d_in[14];
    const float* cb2  = (const float*)d_in[15];
    const float* sw1  = (const float*)d_in[16];
    const float* sb1  = (const float*)d_in[17];
    const float* sw2  = (const float*)d_in[18];
    const float* sb2  = (const float*)d_in[19];
    const float* mw1  = (const float*)d_in[20];
    const float* mb1  = (const float*)d_in[21];
    const float* mw2  = (const float*)d_in[22];
    const float* mb2  = (const float*)d_in[23];
    const float* wgl  = (const float*)d_in[24];
    const float* wch  = (const float*)d_in[25];
    const float* wsp  = (const float*)d_in[26];
    const float* dw   = (const float*)d_in[27];
    const float* db   = (const float*)d_in[28];

    float* ws      = (float*)d_ws;
    float* baseoff = ws;                       // 2*144*6400 = 1,843,200
    float* modb    = baseoff + 1843200;        // 2*72*6400  =   921,600
    float* sbuf    = modb + 921600;            // 2*6400     =    12,800
    float* h1all   = sbuf + 12800;             // 2*192*6400 = 2,457,600
    float* h2      = h1all + 2457600;          // 2*64*6400  =   819,200
    float* xp      = h2 + 819200;              // 1024
    float* scal    = xp + 1024;                // 32

    pool_kernel<<<dim3(512, 2), 256, 0, stream>>>(rgb, th, xp);
    gc_kernel<<<1, 256, 0, stream>>>(xp, gw1, gb1, gw2, gb2, cw1, cb1, cw2, cb2,
                                     wgl, wch, wsp, scal);
    bigconv_kernel<<<dim3(25, 24, 2), 256, 0, stream>>>(rgb, th, ow1, ob1, sw1, sb1,
                                                        mw1, mb1, h1all);
    midconv_kernel<<<dim3(25, 18, 2), 256, 0, stream>>>(h1all, ow2, ob2, sw2, sb2,
                                                        mw2, mb2, h2, sbuf, modb);
    conv3_kernel<<<dim3(25, 18, 2), 256, 0, stream>>>(h2, ow3, ob3, baseoff);
    dcn_kernel<<<dim3(25, 8, 2), 256, 0, stream>>>(rgb, baseoff, modb, sbuf, scal,
                                                   dw, db, (float*)d_out);
}

// Round 11
// 875.009 us; speedup vs baseline: 1.7557x; 1.7557x over previous
//
#include <hip/hip_runtime.h>
#include <cmath>

#define HH 80
#define WW 80
#define HWSZ 6400   // 80*80

using bf16x8 = __attribute__((ext_vector_type(8))) short;
using f32x16 = __attribute__((ext_vector_type(16))) float;
typedef unsigned short u16;

// float -> bf16 (round-nearest-even), as raw bits
__device__ __forceinline__ u16 f2bf(float f) {
    unsigned u = __float_as_uint(f);
    unsigned r = (u + 0x7FFFu + ((u >> 16) & 1u)) >> 16;
    return (u16)r;
}
__device__ __forceinline__ float bf2f(u16 h) {
    return __uint_as_float(((unsigned)h) << 16);
}

// activations: 0=none 1=relu 2=tanh 3=sigmoid 4=softplus
__device__ __forceinline__ float apply_act(float x, int act) {
    switch (act) {
        case 1: return fmaxf(x, 0.f);
        case 2: return tanhf(x);
        case 3: return 1.f / (1.f + expf(-x));
        case 4: return x > 0.f ? x + log1pf(expf(-x)) : log1pf(expf(x));
        default: return x;
    }
}

// ---------------------------------------------------------------------------
// prep_x: padded, ci-chunked bf16 pixel-major image of concat(rgb,th).
// xtp[b][cc(16)][py(84)][px(82)][ci(32)]; halo rows/cols zero (single bf16;
// weights carry the hi/lo precision split). grid (83, 16, 2) x 256.
__global__ __launch_bounds__(256) void prep_x_kernel(
    const float* __restrict__ rgb, const float* __restrict__ th,
    u16* __restrict__ xtp)
{
    const int py = blockIdx.x;      // 0..82
    const int cc = blockIdx.y;      // 0..15
    const int b  = blockIdx.z;
    const int y = py - 1;
    const bool rowok = (y >= 0 && y < HH);
    for (int e = threadIdx.x; e < 82 * 32; e += 256) {
        const int pxp = e % 82;
        const int ci  = e / 82;
        const int x = pxp - 1;
        float v = 0.f;
        if (rowok && x >= 0 && x < WW) {
            const int c = cc * 32 + ci;
            const float* src = (c < 256) ? rgb + (b * 256 + c) * HWSZ
                                         : th + (b * 256 + (c - 256)) * HWSZ;
            v = src[y * WW + x];
        }
        xtp[((b * 16 + cc) * 84 + py) * 2624 + pxp * 32 + ci] = f2bf(v);
    }
}

// ---------------------------------------------------------------------------
// prep_w: pack the three 512->64 conv weights into MFMA A-fragment order,
// hi/lo split. apack[cg(6)][t(9)][cc(16)][sub(2)][lane(64)][j(8)], lo at
// +884,736. co = (cg&1)*32+(lane&31), ci = cc*32+sub*16+(lane>>5)*8+j,
// branch = cg>>1 in {ow1, sw1, mw1}. grid 432 x 256.
__global__ __launch_bounds__(256) void prep_w_kernel(
    const float* __restrict__ ow1, const float* __restrict__ sw1,
    const float* __restrict__ mw1, u16* __restrict__ apack)
{
    const int id = blockIdx.x * 256 + threadIdx.x;   // 0..110591 exact
    const int l = id & 63;
    const int sub = (id >> 6) & 1;
    const int cc = (id >> 7) & 15;
    const int tmp = id >> 11;      // cg*9 + t
    const int t = tmp % 9;
    const int cg = tmp / 9;        // 0..5
    const int br = cg >> 1;
    const float* w = (br == 0) ? ow1 : (br == 1) ? sw1 : mw1;
    const int co = (cg & 1) * 32 + (l & 31);
    const int ci0 = cc * 32 + sub * 16 + (l >> 5) * 8;
    const int base = id * 8;
#pragma unroll
    for (int j = 0; j < 8; ++j) {
        const float v = w[(co * 512 + ci0 + j) * 9 + t];
        const u16 h = f2bf(v);
        apack[base + j] = h;
        apack[884736 + base + j] = f2bf(v - bf2f(h));
    }
}

// ---------------------------------------------------------------------------
// prep_w2: pack the 64-ci conv weights (ow2, sw2, mw2, ow3), hi/lo split.
// 14 cg-groups: 0,1=ow2(64); 2,3=sw2(1,pad); 4..7=mw2(72,pad); 8..13=ow3
// (144,pad). id = (((cg*9+t)*2+cc)*2+sub)*64+l; elem at id*8+j; lo +258,048.
// grid 126 x 256 (= 32,256 ids exact).
// NOTE: launched AFTER gemm_conv1 — apack2 lives in the dead-xtp region.
__global__ __launch_bounds__(256) void prep_w2_kernel(
    const float* __restrict__ ow2, const float* __restrict__ sw2,
    const float* __restrict__ mw2, const float* __restrict__ ow3,
    u16* __restrict__ apack2)
{
    const int id = blockIdx.x * 256 + threadIdx.x;   // 0..32255
    const int l = id & 63;
    const int sub = (id >> 6) & 1;
    const int cc = (id >> 7) & 1;
    const int tmp = id >> 8;       // cg*9 + t, 0..125
    const int t = tmp % 9;
    const int cg = tmp / 9;        // 0..13
    const float* w;
    int Cout, coBase;
    if (cg < 2)      { w = ow2; Cout = 64;  coBase = cg * 32; }
    else if (cg < 4) { w = sw2; Cout = 1;   coBase = (cg - 2) * 32; }
    else if (cg < 8) { w = mw2; Cout = 72;  coBase = (cg - 4) * 32; }
    else             { w = ow3; Cout = 144; coBase = (cg - 8) * 32; }
    const int co = coBase + (l & 31);
    const int ci0 = cc * 32 + sub * 16 + (l >> 5) * 8;
    const int base = id * 8;
#pragma unroll
    for (int j = 0; j < 8; ++j) {
        const float v = (co < Cout) ? w[(co * 64 + ci0 + j) * 9 + t] : 0.f;
        const u16 h = f2bf(v);
        apack2[base + j] = h;
        apack2[258048 + base + j] = f2bf(v - bf2f(h));
    }
}

// ---------------------------------------------------------------------------
// zero_hp: zero the whole hp buffer (3,526,656 u16 = 440,832 uint4) so the
// pad halo is 0 before the gemms write interiors. ws is re-poisoned to 0xAA
// before every timed launch, so this must run every call.
__global__ __launch_bounds__(256) void zero_hp_kernel(uint4* __restrict__ hp4)
{
    const int n = 440832;
    const uint4 z = make_uint4(0u, 0u, 0u, 0u);
    for (int i = blockIdx.x * 256 + threadIdx.x; i < n; i += gridDim.x * 256)
        hp4[i] = z;
}

// ---------------------------------------------------------------------------
// gemm_conv1: the three 512->64 3x3 convs as implicit GEMM on
// mfma_f32_32x32x16_bf16 (weights hi/lo -> 2 MFMA per K16-step).
// Block: 256 thr = 4 waves; tile co64 x px64; wave (wr,pg) owns one 32x32
// frag. Output written directly as bf16 into hp chunks 0..5 (+ zero halo).
// grid (100 px-tiles, 3 branches, 2 batch).
__global__ __launch_bounds__(256) void gemm_conv1_kernel(
    const u16* __restrict__ xtp, const u16* __restrict__ apack,
    const float* __restrict__ ob1, const float* __restrict__ sb1,
    const float* __restrict__ mb1, u16* __restrict__ hp)
{
    const int tid = threadIdx.x;
    const int l = tid & 63;
    const int wv = tid >> 6;
    const int wr = wv & 1, pg = wv >> 1;
    const int pxBase = blockIdx.x * 64;
    const int cb = blockIdx.y;
    const int b = blockIdx.z;
    const int y0 = pxBase / 80;
    const int n = pxBase + pg * 32 + (l & 31);
    const int ny = n / 80, nx = n % 80;
    const int ryb = ny - y0;          // 0 or 1
    const int lh = l >> 5;
    const int cg = cb * 2 + wr;

    // win[cig(4)][ry(4)][col(82)][8ci] = 10,496 shorts = 20.5 KiB
    __shared__ u16 win[4 * 4 * 82 * 8];

    f32x16 acc;
#pragma unroll
    for (int r = 0; r < 16; ++r) acc[r] = 0.f;

    const u16* xb = xtp + b * (16 * 84 * 2624);

    for (int cc = 0; cc < 16; ++cc) {
        // stage 32-ci window: rows y0..y0+3 (padded), full width
        for (int i = tid; i < 1312; i += 256) {
            const int col = i % 82;
            const int q = i / 82;          // 0..15
            const int ry = q & 3, cig = q >> 2;
            const int src = (cc * 84 + (y0 + ry)) * 2624 + col * 32 + cig * 8;
            const bf16x8 v = *(const bf16x8*)(xb + src);
            *(bf16x8*)(win + ((cig * 4 + ry) * 82 + col) * 8) = v;
        }
        __syncthreads();

#pragma unroll
        for (int t = 0; t < 9; ++t) {
            const int ry = ryb + (t / 3);
            const int col = nx + (t % 3);
            const int po = (ry * 82 + col) * 8;
#pragma unroll
            for (int sub = 0; sub < 2; ++sub) {
                const int cig = sub * 2 + lh;
                const bf16x8 bh = *(const bf16x8*)(win + cig * 2624 + po);
                const int ao = ((cg * 9 + t) * 16 + cc) * 1024 + sub * 512 + l * 8;
                const bf16x8 ah = *(const bf16x8*)(apack + ao);
                const bf16x8 al = *(const bf16x8*)(apack + 884736 + ao);
                acc = __builtin_amdgcn_mfma_f32_32x32x16_bf16(ah, bh, acc, 0, 0, 0);
                acc = __builtin_amdgcn_mfma_f32_32x32x16_bf16(al, bh, acc, 0, 0, 0);
            }
        }
        __syncthreads();
    }

    // epilogue: bias + relu -> bf16 direct into hp chunk cb*2+wr.
    // C/D layout: col=l&31 (pixel), row=(r&3)+8*(r>>2)+4*lh (co%32).
    const float* bias = (cb == 0) ? ob1 : (cb == 1) ? sb1 : mb1;
    const int ch = cb * 2 + wr;
    const int pixbase = ((b * 8 + ch) * 84 + (ny + 1)) * 2624 + (nx + 1) * 32;
#pragma unroll
    for (int r = 0; r < 16; ++r) {
        const int row = (r & 3) + 8 * (r >> 2) + 4 * lh;
        const int co = wr * 32 + row;
        const float v = fmaxf(acc[r] + bias[co], 0.f);
        hp[pixbase + row] = f2bf(v);
    }
}

// ---------------------------------------------------------------------------
// gemm64_tile: shared K-loop for the 64-ci conv layers (2 ci-chunks).
// hp[b][chunk8][84][82][32] single bf16; apack2 hi at 0, lo at +258,048.
__device__ __forceinline__ void gemm64_tile(
    const u16* __restrict__ hp, const u16* __restrict__ apack2,
    int b, int pxBase, int chunk0, int cgBase, f32x16& acc)
{
    const int tid = threadIdx.x;
    const int l = tid & 63;
    const int wv = tid >> 6;
    const int wr = wv & 1, pg = wv >> 1;
    const int y0 = pxBase / 80;
    const int n = pxBase + pg * 32 + (l & 31);
    const int nx = n % 80;
    const int ryb = (n / 80) - y0;
    const int lh = l >> 5;
    const int cg = cgBase + wr;

    __shared__ u16 win[4 * 4 * 82 * 8];

#pragma unroll
    for (int r = 0; r < 16; ++r) acc[r] = 0.f;

    const u16* xb = hp + b * (8 * 84 * 2624);

    for (int ccl = 0; ccl < 2; ++ccl) {
        const int ch = chunk0 + ccl;
        for (int i = tid; i < 1312; i += 256) {
            const int col = i % 82;
            const int q = i / 82;          // 0..15
            const int ry = q & 3, cig = q >> 2;
            const int src = (ch * 84 + (y0 + ry)) * 2624 + col * 32 + cig * 8;
            const bf16x8 v = *(const bf16x8*)(xb + src);
            *(bf16x8*)(win + ((cig * 4 + ry) * 82 + col) * 8) = v;
        }
        __syncthreads();

#pragma unroll
        for (int t = 0; t < 9; ++t) {
            const int ry = ryb + (t / 3);
            const int col = nx + (t % 3);
            const int po = (ry * 82 + col) * 8;
#pragma unroll
            for (int sub = 0; sub < 2; ++sub) {
                const int cig = sub * 2 + lh;
                const bf16x8 bh = *(const bf16x8*)(win + cig * 2624 + po);
                const int ao = ((cg * 9 + t) * 2 + ccl) * 1024 + sub * 512 + l * 8;
                const bf16x8 ah = *(const bf16x8*)(apack2 + ao);
                const bf16x8 al = *(const bf16x8*)(apack2 + 258048 + ao);
                acc = __builtin_amdgcn_mfma_f32_32x32x16_bf16(ah, bh, acc, 0, 0, 0);
                acc = __builtin_amdgcn_mfma_f32_32x32x16_bf16(al, bh, acc, 0, 0, 0);
            }
        }
        __syncthreads();
    }
}

// gemm_mid: y=0 conv2(relu)->hp chunks 6,7 (bf16); y=1 sw2(softplus)->sbuf;
// y=2,3 mw2(sigmoid)->modb. grid (100, 4, 2).
__global__ __launch_bounds__(256) void gemm_mid_kernel(
    const u16* __restrict__ hpc, u16* __restrict__ hp,
    const u16* __restrict__ apack2,
    const float* __restrict__ ob2, const float* __restrict__ sb2,
    const float* __restrict__ mb2,
    float* __restrict__ sbuf, float* __restrict__ modb)
{
    const int y = blockIdx.y, b = blockIdx.z;
    const int chunk0 = (y == 0) ? 0 : (y == 1) ? 2 : 4;
    f32x16 acc;
    gemm64_tile(hpc, apack2, b, blockIdx.x * 64, chunk0, y * 2, acc);

    const int l = threadIdx.x & 63;
    const int wv = threadIdx.x >> 6;
    const int wr = wv & 1, pg = wv >> 1;
    const int lh = l >> 5;
    const int colpx = blockIdx.x * 64 + pg * 32 + (l & 31);
    const int ny = colpx / 80, nx = colpx % 80;
#pragma unroll
    for (int r = 0; r < 16; ++r) {
        const int row = (r & 3) + 8 * (r >> 2) + 4 * lh;
        const int co = wr * 32 + row;
        if (y == 0) {
            const float v = fmaxf(acc[r] + ob2[co], 0.f);
            hp[((b * 8 + 6 + wr) * 84 + (ny + 1)) * 2624 + (nx + 1) * 32 + row] = f2bf(v);
        } else if (y == 1) {
            if (co == 0)
                sbuf[b * HWSZ + colpx] = apply_act(acc[r] + sb2[0], 4);
        } else {
            const int cog = (y - 2) * 64 + co;
            if (cog < 72)
                modb[(b * 72 + cog) * HWSZ + colpx] =
                    apply_act(acc[r] + mb2[cog], 3);
        }
    }
}

// gemm_c3: ow3 (tanh) -> baseoff, 144 co in 3 co-tiles. grid (100, 3, 2).
__global__ __launch_bounds__(256) void gemm_c3_kernel(
    const u16* __restrict__ hp, const u16* __restrict__ apack2,
    const float* __restrict__ ob3, float* __restrict__ baseoff)
{
    const int y = blockIdx.y, b = blockIdx.z;
    f32x16 acc;
    gemm64_tile(hp, apack2, b, blockIdx.x * 64, 6, 8 + y * 2, acc);

    const int l = threadIdx.x & 63;
    const int wv = threadIdx.x >> 6;
    const int wr = wv & 1, pg = wv >> 1;
    const int lh = l >> 5;
    const int colpx = blockIdx.x * 64 + pg * 32 + (l & 31);
#pragma unroll
    for (int r = 0; r < 16; ++r) {
        const int row = (r & 3) + 8 * (r >> 2) + 4 * lh;
        const int co = y * 64 + wr * 32 + row;
        if (co < 144)
            baseoff[(b * 144 + co) * HWSZ + colpx] = tanhf(acc[r] + ob3[co]);
    }
}

// ---------------------------------------------------------------------------
// Global average pool: one block per (channel, b). grid (512, B)
__global__ __launch_bounds__(256) void pool_kernel(
    const float* __restrict__ rgb, const float* __restrict__ th,
    float* __restrict__ xp)
{
    const int c = blockIdx.x, b = blockIdx.y, tid = threadIdx.x;
    const float* src = (c < 256) ? rgb + (b * 256 + c) * HWSZ
                                 : th + (b * 256 + (c - 256)) * HWSZ;
    float s = 0.f;
    for (int i = tid; i < HWSZ; i += 256) s += src[i];
#pragma unroll
    for (int off = 32; off; off >>= 1) s += __shfl_down(s, off, 64);
    __shared__ float red[4];
    if ((tid & 63) == 0) red[tid >> 6] = s;
    __syncthreads();
    if (tid == 0) xp[b * 512 + c] = (red[0] + red[1] + red[2] + red[3]) * (1.f / HWSZ);
}

// Tiny MLPs for g (512->32->1) and c (512->256->8), plus softmax of 3 scalars.
// scal layout: [0..2]=wts, [3..4]=g per b, [5..20]=c per (b, group)
__global__ __launch_bounds__(256) void gc_kernel(
    const float* __restrict__ xp,
    const float* __restrict__ gw1, const float* __restrict__ gb1,
    const float* __restrict__ gw2, const float* __restrict__ gb2,
    const float* __restrict__ cw1, const float* __restrict__ cb1,
    const float* __restrict__ cw2, const float* __restrict__ cb2,
    const float* __restrict__ wglob, const float* __restrict__ wchan,
    const float* __restrict__ wspat,
    float* __restrict__ scal)
{
    const int tid = threadIdx.x;
    const int lane = tid & 63;
    const int wv = tid >> 6;
    __shared__ float xs[512];
    __shared__ float hg[32];
    __shared__ float hc[256];

    if (tid == 0) {
        float a = wglob[0], bb = wchan[0], cc = wspat[0];
        float mx = fmaxf(a, fmaxf(bb, cc));
        float ea = expf(a - mx), eb = expf(bb - mx), ec = expf(cc - mx);
        float s = ea + eb + ec;
        scal[0] = ea / s; scal[1] = eb / s; scal[2] = ec / s;
    }

    for (int b = 0; b < 2; ++b) {
        xs[tid] = xp[b * 512 + tid];
        xs[tid + 256] = xp[b * 512 + 256 + tid];
        __syncthreads();
        for (int j = wv; j < 256; j += 4) {
            float s = 0.f;
            for (int i = lane; i < 512; i += 64) s = fmaf(cw1[j * 512 + i], xs[i], s);
#pragma unroll
            for (int o = 32; o; o >>= 1) s += __shfl_down(s, o, 64);
            if (lane == 0) hc[j] = fmaxf(s + cb1[j], 0.f);
        }
        for (int j = wv; j < 32; j += 4) {
            float s = 0.f;
            for (int i = lane; i < 512; i += 64) s = fmaf(gw1[j * 512 + i], xs[i], s);
#pragma unroll
            for (int o = 32; o; o >>= 1) s += __shfl_down(s, o, 64);
            if (lane == 0) hg[j] = fmaxf(s + gb1[j], 0.f);
        }
        __syncthreads();
        for (int j = wv; j < 8; j += 4) {
            float s = 0.f;
            for (int i = lane; i < 256; i += 64) s = fmaf(cw2[j * 256 + i], hc[i], s);
#pragma unroll
            for (int o = 32; o; o >>= 1) s += __shfl_down(s, o, 64);
            if (lane == 0) scal[5 + b * 8 + j] = apply_act(s + cb2[j], 4);
        }
        if (wv == 1) {
            float s = (lane < 32) ? gw2[lane] * hg[lane] : 0.f;
#pragma unroll
            for (int o = 32; o; o >>= 1) s += __shfl_down(s, o, 64);
            if (lane == 0) scal[3 + b] = apply_act(s + gb2[0], 4);
        }
        __syncthreads();
    }
}

// ---------------------------------------------------------------------------
// Modulated deformable conv. One thread = one pixel of one group; 32 output
// channel accumulators. grid: (25, G=8, B)
__global__ __launch_bounds__(256) void dcn_kernel(
    const float* __restrict__ rgb, const float* __restrict__ baseoff,
    const float* __restrict__ modb, const float* __restrict__ sbuf,
    const float* __restrict__ scal,
    const float* __restrict__ dw, const float* __restrict__ db,
    float* __restrict__ out)
{
    const int tid = threadIdx.x;
    const int p = blockIdx.x * 256 + tid;
    const int g = blockIdx.y, b = blockIdx.z;
    const int h = p / 80, wp = p - h * 80;

    const float w0 = scal[0], w1 = scal[1], w2 = scal[2];
    const float gv = scal[3 + b];
    const float sv = sbuf[b * HWSZ + p];
    const float basegs = w0 * gv + w2 * sv;

    const float* xg = rgb + (b * 256 + g * 32) * HWSZ;
    const float* wt = dw + (g * 32) * 32 * 9;

    float acc[32];
#pragma unroll
    for (int o = 0; o < 32; ++o) acc[o] = 0.f;

    for (int k = 0; k < 9; ++k) {
        const int chy = g * 18 + k * 2;
        const int chx = chy + 1;
        const int jy = (chy % 72) / 9;
        const int jx = (chx % 72) / 9;
        const float cmy = basegs + w1 * scal[5 + b * 8 + jy];
        const float cmx = basegs + w1 * scal[5 + b * 8 + jx];
        const float offy = baseoff[(b * 144 + chy) * HWSZ + p] * cmy;
        const float offx = baseoff[(b * 144 + chx) * HWSZ + p] * cmx;

        const float py = (float)(h + (k / 3) - 1) + offy;
        const float px = (float)(wp + (k % 3) - 1) + offx;
        const float y0f = floorf(py), x0f = floorf(px);
        const float ly = py - y0f, lx = px - x0f;
        const int iy0 = (int)y0f, ix0 = (int)x0f;
        const int iy1 = iy0 + 1, ix1 = ix0 + 1;

        const float m = modb[(b * 72 + g * 9 + k) * HWSZ + p];

        const float vy0 = (iy0 >= 0 && iy0 < HH) ? 1.f : 0.f;
        const float vy1 = (iy1 >= 0 && iy1 < HH) ? 1.f : 0.f;
        const float vx0 = (ix0 >= 0 && ix0 < WW) ? 1.f : 0.f;
        const float vx1 = (ix1 >= 0 && ix1 < WW) ? 1.f : 0.f;
        const int cy0 = min(max(iy0, 0), HH - 1), cy1 = min(max(iy1, 0), HH - 1);
        const int cx0 = min(max(ix0, 0), WW - 1), cx1 = min(max(ix1, 0), WW - 1);

        const float w00 = (1.f - ly) * (1.f - lx) * vy0 * vx0 * m;
        const float w01 = (1.f - ly) * lx * vy0 * vx1 * m;
        const float w10 = ly * (1.f - lx) * vy1 * vx0 * m;
        const float w11 = ly * lx * vy1 * vx1 * m;

        const int i00 = cy0 * WW + cx0, i01 = cy0 * WW + cx1;
        const int i10 = cy1 * WW + cx0, i11 = cy1 * WW + cx1;

#pragma unroll 8
        for (int c = 0; c < 32; ++c) {
            const float* xc = xg + c * HWSZ;
            float v = w00 * xc[i00] + w01 * xc[i01] + w10 * xc[i10] + w11 * xc[i11];
            const float* wck = wt + c * 9 + k;
#pragma unroll
            for (int o = 0; o < 32; ++o) acc[o] = fmaf(wck[o * 288], v, acc[o]);
        }
    }

#pragma unroll
    for (int o = 0; o < 32; ++o)
        out[(b * 256 + g * 32 + o) * HWSZ + p] = acc[o] + db[g * 32 + o];
}

// ---------------------------------------------------------------------------
extern "C" void kernel_launch(void* const* d_in, const int* in_sizes, int n_in,
                              void* d_out, int out_size, void* d_ws, size_t ws_size,
                              hipStream_t stream) {
    const float* rgb  = (const float*)d_in[0];
    const float* th   = (const float*)d_in[1];
    const float* ow1  = (const float*)d_in[2];
    const float* ob1  = (const float*)d_in[3];
    const float* ow2  = (const float*)d_in[4];
    const float* ob2  = (const float*)d_in[5];
    const float* ow3  = (const float*)d_in[6];
    const float* ob3  = (const float*)d_in[7];
    const float* gw1  = (const float*)d_in[8];
    const float* gb1  = (const float*)d_in[9];
    const float* gw2  = (const float*)d_in[10];
    const float* gb2  = (const float*)d_in[11];
    const float* cw1  = (const float*)d_in[12];
    const float* cb1  = (const float*)d_in[13];
    const float* cw2  = (const float*)d_in[14];
    const float* cb2  = (const float*)d_in[15];
    const float* sw1  = (const float*)d_in[16];
    const float* sb1  = (const float*)d_in[17];
    const float* sw2  = (const float*)d_in[18];
    const float* sb2  = (const float*)d_in[19];
    const float* mw1  = (const float*)d_in[20];
    const float* mb1  = (const float*)d_in[21];
    const float* mw2  = (const float*)d_in[22];
    const float* mb2  = (const float*)d_in[23];
    const float* wgl  = (const float*)d_in[24];
    const float* wch  = (const float*)d_in[25];
    const float* wsp  = (const float*)d_in[26];
    const float* dw   = (const float*)d_in[27];
    const float* db   = (const float*)d_in[28];

    float* ws = (float*)d_ws;
    // ws layout (float offsets), peak 6,175,776 f = 24.70 MB:
    //  xp    [0, 1,024);  scal [1,024, 1,056)
    //  xtp   u16 @ 1,056 (7,053,312 u16 = 3,526,656 f) live prep_x->gemm_conv1
    //    after gemm_conv1, dead xtp hosts (stream-ordered):
    //      baseoff f32 @ 1,056      (1,843,200) -> ends 1,844,256
    //      modb    f32 @ 1,844,256  (921,600)   -> ends 2,765,856
    //      sbuf    f32 @ 2,765,856  (12,800)    -> ends 2,778,656
    //      apack2  u16 @ 2,778,656  (516,096 u16 = 258,048 f) -> ends 3,036,704
    //  hp    u16 @ 3,527,712 (3,526,656 u16 = 1,763,328 f) -> ends 5,291,040
    //  apack u16 @ 5,291,040 (1,769,472 u16 = 884,736 f)   -> ends 6,175,776
    float* xp      = ws;
    float* scal    = ws + 1024;
    u16*   xtp     = (u16*)(ws + 1056);
    float* baseoff = ws + 1056;
    float* modb    = ws + 1844256;
    float* sbuf    = ws + 2765856;
    u16*   apack2  = (u16*)(ws + 2778656);
    u16*   hp      = (u16*)(ws + 3527712);
    u16*   apack   = (u16*)(ws + 5291040);

    pool_kernel<<<dim3(512, 2), 256, 0, stream>>>(rgb, th, xp);
    gc_kernel<<<1, 256, 0, stream>>>(xp, gw1, gb1, gw2, gb2, cw1, cb1, cw2, cb2,
                                     wgl, wch, wsp, scal);
    prep_x_kernel<<<dim3(83, 16, 2), 256, 0, stream>>>(rgb, th, xtp);
    prep_w_kernel<<<432, 256, 0, stream>>>(ow1, sw1, mw1, apack);
    zero_hp_kernel<<<1024, 256, 0, stream>>>((uint4*)hp);
    gemm_conv1_kernel<<<dim3(100, 3, 2), 256, 0, stream>>>(xtp, apack,
                                                           ob1, sb1, mb1, hp);
    // prep_w2 AFTER gemm_conv1: apack2 aliases the now-dead xtp region.
    prep_w2_kernel<<<126, 256, 0, stream>>>(ow2, sw2, mw2, ow3, apack2);
    gemm_mid_kernel<<<dim3(100, 4, 2), 256, 0, stream>>>(hp, hp, apack2,
                                                         ob2, sb2, mb2,
                                                         sbuf, modb);
    gemm_c3_kernel<<<dim3(100, 3, 2), 256, 0, stream>>>(hp, apack2, ob3, baseoff);
    dcn_kernel<<<dim3(25, 8, 2), 256, 0, stream>>>(rgb, baseoff, modb, sbuf, scal,
                                                   dw, db, (float*)d_out);
}